// Round 1
// baseline (138.854 us; speedup 1.0000x reference)
//
#include <hip/hip_runtime.h>
#include <math.h>

#define NN 8192
#define FF 128
#define CAP 128

__device__ __forceinline__ float wave_max(float v) {
  #pragma unroll
  for (int off = 32; off > 0; off >>= 1) v = fmaxf(v, __shfl_down(v, off));
  return v;
}
__device__ __forceinline__ float wave_sum(float v) {
  #pragma unroll
  for (int off = 32; off > 0; off >>= 1) v += __shfl_down(v, off);
  return v;
}

// --- per-row attention dots: f1[i] = x[i]·a[0:128], f2[i] = x[i]·a[128:256]
__global__ __launch_bounds__(256) void k_scores(const float* __restrict__ x,
                                                const float* __restrict__ a,
                                                float* __restrict__ f1,
                                                float* __restrict__ f2) {
  int gid = blockIdx.x * blockDim.x + threadIdx.x;
  int row = gid >> 6;
  int lane = gid & 63;
  if (row >= NN) return;
  const float* xr = x + (size_t)row * FF;
  float v0 = xr[lane], v1 = xr[lane + 64];
  float s1 = v0 * a[lane] + v1 * a[lane + 64];
  float s2 = v0 * a[FF + lane] + v1 * a[FF + lane + 64];
  #pragma unroll
  for (int off = 32; off > 0; off >>= 1) {
    s1 += __shfl_down(s1, off);
    s2 += __shfl_down(s2, off);
  }
  if (lane == 0) { f1[row] = s1; f2[row] = s2; }
}

// --- one block per row: stream adj row, compact nonzeros, softmax, U@x, feat
__global__ __launch_bounds__(256) void k_build(
    const float* __restrict__ adj, const float* __restrict__ x,
    const float* __restrict__ f1g, const float* __restrict__ f2g,
    const float* __restrict__ temp,
    int* __restrict__ nnzg, int* __restrict__ colsg, float* __restrict__ valsg,
    float* __restrict__ rowsumg, float* __restrict__ featg) {
  const int row = blockIdx.x;
  const int t = threadIdx.x;
  const int lane = t & 63, w = t >> 6;

  __shared__ int   s_cols[CAP];
  __shared__ float s_u[CAP];
  __shared__ int   s_scan[4];
  __shared__ int   s_total;
  __shared__ float s_red[4];
  __shared__ float s_m, s_s, s_r2;
  __shared__ float s_part[256];

  // ---- deterministic compaction of nonzero columns (ascending order) ----
  const float4* arow = (const float4*)(adj + (size_t)row * NN);
  int base = 0;
  for (int it = 0; it < 8; ++it) {
    int idx4 = it * 256 + t;
    float4 v = arow[idx4];
    int c0 = v.x > 0.f, c1 = v.y > 0.f, c2 = v.z > 0.f, c3 = v.w > 0.f;
    int cnt = c0 + c1 + c2 + c3;
    // wave inclusive scan
    int incl = cnt;
    #pragma unroll
    for (int off = 1; off < 64; off <<= 1) {
      int nb = __shfl_up(incl, off);
      if (lane >= off) incl += nb;
    }
    if (lane == 63) s_scan[w] = incl;
    __syncthreads();
    if (t == 0) {
      int acc = 0;
      #pragma unroll
      for (int i = 0; i < 4; ++i) { int vv = s_scan[i]; s_scan[i] = acc; acc += vv; }
      s_total = acc;
    }
    __syncthreads();
    int pos = base + s_scan[w] + (incl - cnt);
    int j0 = idx4 * 4;
    if (c0) { if (pos < CAP) s_cols[pos] = j0;     pos++; }
    if (c1) { if (pos < CAP) s_cols[pos] = j0 + 1; pos++; }
    if (c2) { if (pos < CAP) s_cols[pos] = j0 + 2; pos++; }
    if (c3) { if (pos < CAP) s_cols[pos] = j0 + 3; pos++; }
    base += s_total;
    __syncthreads();
  }
  int cnt = base < CAP ? base : CAP;

  // ---- e = leakyrelu(f1[i] + f2[j]); row max ----
  float F1 = f1g[row];
  float m = -INFINITY;
  for (int k = t; k < cnt; k += 256) {
    float s = F1 + f2g[s_cols[k]];
    float e = s > 0.f ? s : 0.2f * s;
    s_u[k] = e;
    m = fmaxf(m, e);
  }
  m = wave_max(m);
  if (lane == 0) s_red[w] = m;
  __syncthreads();
  if (t == 0) s_m = fmaxf(fmaxf(s_red[0], s_red[1]), fmaxf(s_red[2], s_red[3]));
  __syncthreads();
  m = s_m;

  // ---- exp & sum ----
  float ssum = 0.f;
  for (int k = t; k < cnt; k += 256) {
    float p = expf(s_u[k] - m);
    s_u[k] = p;
    ssum += p;
  }
  ssum = wave_sum(ssum);
  if (lane == 0) s_red[w] = ssum;
  __syncthreads();
  if (t == 0) s_s = s_red[0] + s_red[1] + s_red[2] + s_red[3];
  __syncthreads();
  float inv = 1.f / s_s;

  // ---- normalize, rowsum = 0.5*sum(U^2) ----
  float su2 = 0.f;
  for (int k = t; k < cnt; k += 256) {
    float u = s_u[k] * inv;
    s_u[k] = u;
    su2 += u * u;
  }
  su2 = wave_sum(su2);
  __syncthreads();          // ensure previous s_red reads done
  if (lane == 0) s_red[w] = su2;
  __syncthreads();
  if (t == 0) s_r2 = 0.5f * (s_red[0] + s_red[1] + s_red[2] + s_red[3]);
  __syncthreads();
  float rsum = s_r2;

  // ---- persist sparse row ----
  if (t == 0) { nnzg[row] = cnt; rowsumg[row] = rsum; }
  int* cg = colsg + (size_t)row * CAP;
  float* vg = valsg + (size_t)row * CAP;
  for (int k = t; k < cnt; k += 256) { cg[k] = s_cols[k]; vg[k] = s_u[k]; }
  __syncthreads();

  // ---- prop_u = U @ x ; feat = prop_u - x*rowsum + (1-coe2)*x ----
  float coe2 = 1.f / (1.f + expf(-temp[2]));
  int f = t & 127, half = t >> 7;
  float acc = 0.f;
  for (int k = half; k < cnt; k += 2)
    acc += s_u[k] * x[(size_t)s_cols[k] * FF + f];
  s_part[t] = acc;
  __syncthreads();
  if (t < FF) {
    float prop = s_part[t] + s_part[t + FF];
    float xv = x[(size_t)row * FF + t];
    featg[(size_t)row * FF + t] = prop - xv * rsum + (1.f - coe2) * xv;
  }
}

// --- second SpMM + inverse lifting + output blend
__global__ __launch_bounds__(256) void k_apply(
    const float* __restrict__ featg, const float* __restrict__ h0,
    const float* __restrict__ temp,
    const int* __restrict__ nnzg, const int* __restrict__ colsg,
    const float* __restrict__ valsg, const float* __restrict__ rowsumg,
    float* __restrict__ out) {
  const int row = blockIdx.x;
  const int t = threadIdx.x;
  __shared__ int   s_cols[CAP];
  __shared__ float s_u[CAP];
  __shared__ float s_part[256];
  int cnt = nnzg[row];
  const int* cg = colsg + (size_t)row * CAP;
  const float* vg = valsg + (size_t)row * CAP;
  if (t < cnt) { s_cols[t] = cg[t]; s_u[t] = vg[t]; }
  __syncthreads();
  int f = t & 127, half = t >> 7;
  float acc = 0.f;
  for (int k = half; k < cnt; k += 2)
    acc += s_u[k] * featg[(size_t)s_cols[k] * FF + f];
  s_part[t] = acc;
  __syncthreads();
  if (t < FF) {
    float prop2 = s_part[t] + s_part[t + FF];
    float ft = featg[(size_t)row * FF + t];
    float rs = rowsumg[row];
    float coe1 = 1.f / (1.f + expf(-temp[1]));
    float coe3 = 1.f / (1.f + expf(-temp[3]));
    float odd = ft - prop2;
    float even = coe3 * prop2 + odd * rs;
    float fp = coe1 * even + (1.f - coe1) * odd;
    out[(size_t)row * FF + t] = 0.2f * fp + 0.8f * h0[(size_t)row * FF + t];
  }
}

extern "C" void kernel_launch(void* const* d_in, const int* in_sizes, int n_in,
                              void* d_out, int out_size, void* d_ws, size_t ws_size,
                              hipStream_t stream) {
  const float* x    = (const float*)d_in[0];
  const float* h0   = (const float*)d_in[1];
  const float* adj  = (const float*)d_in[2];
  const float* a    = (const float*)d_in[3];
  const float* temp = (const float*)d_in[4];
  float* out = (float*)d_out;

  float* f1 = (float*)d_ws;
  float* f2 = f1 + NN;
  float* rowsum = f2 + NN;
  int*   nnz = (int*)(rowsum + NN);
  int*   cols = nnz + NN;
  float* vals = (float*)(cols + (size_t)NN * CAP);
  float* feat = vals + (size_t)NN * CAP;

  k_scores<<<NN / 4, 256, 0, stream>>>(x, a, f1, f2);
  k_build<<<NN, 256, 0, stream>>>(adj, x, f1, f2, temp, nnz, cols, vals, rowsum, feat);
  k_apply<<<NN, 256, 0, stream>>>(feat, h0, temp, nnz, cols, vals, rowsum, out);
}